// Round 4
// baseline (1589.615 us; speedup 1.0000x reference)
//
#include <hip/hip_runtime.h>

// gamma_{t+1}[j] = clip(sum_e w[e]*gamma_t[nbr[e]] + residual[j], 0, 1), 10 steps.
// R8: bucketed-LDS SpMV. R7 post-mortem: random 4B gathers from the 800KB gamma
// are capped by per-CU L1 miss-handling (~0.35 gathers/cyc measured); nt hurt
// (FETCH 63->81MB: it defeats L3 retention). Fix: gather from LDS instead.
//  - prep: per-row counting sort of edges by neighbor bucket (nbr>>14), wave-level
//    ballot sort fused with quantize/pack/residual (sortpack kernel).
//  - step_lds: 512 thr, 64KB LDS slice, 2 blocks/CU, exactly 512 blocks; per bucket:
//    coalesced slice load (L2) then ds_read gathers. L1 bypassed entirely.
// Edge pack u32: high 14 bits = round(bl * 2^21) (bl < 2^-7), low 18 bits = nbr.

#define NBR_MASK 0x3FFFFu
#define Q_SCALE 2097152.0f            // 2^21
#define Q_INV   4.76837158203125e-07f // 2^-21
#define BSHIFT 14
#define BSIZE  16384                   // floats per bucket slice (64 KB)

typedef unsigned uint32x4 __attribute__((ext_vector_type(4)));
typedef float    floatx4  __attribute__((ext_vector_type(4)));

__device__ __forceinline__ unsigned quantize(float b) {
    unsigned q = (unsigned)(b * Q_SCALE + 0.5f);
    return q > 16383u ? 16383u : q;
}
__device__ __forceinline__ float clip01(float x) { return fminf(fmaxf(x, 0.f), 1.f); }

// row_ptr[j] = first edge index with seg >= j.
__global__ void build_rowptr(const int* __restrict__ seg, int* __restrict__ row_ptr,
                             int n_edges, int n_part) {
    int e = blockIdx.x * blockDim.x + threadIdx.x;
    if (e >= n_edges) return;
    int s = seg[e];
    int sprev = (e == 0) ? -1 : seg[e - 1];
    for (int j = sprev + 1; j <= s; ++j) row_ptr[j] = e;
    if (e == n_edges - 1)
        for (int j = s + 1; j <= n_part; ++j) row_ptr[j] = n_edges;
}

// One wave per row: counting-sort edges by bucket (ballot/popc), write packed
// sorted edges + per-(row,bucket) pointers + residual + gamma1.
__global__ __launch_bounds__(256) void sortpack(const float* __restrict__ bl,
        const int* __restrict__ nbr, const int* __restrict__ row_ptr,
        unsigned* __restrict__ pack, int* __restrict__ rbptr,
        float* __restrict__ residual, float* __restrict__ g1,
        int n_part, int nb) {
    int row  = (blockIdx.x * 256 + threadIdx.x) >> 6;
    int lane = threadIdx.x & 63;
    if (row >= n_part) return;
    int start = row_ptr[row], end = row_ptr[row + 1];
    int deg = end - start;

    // pass 1: per-bucket counts (lane L accumulates count of bucket L)
    int myCount = 0;
    for (int base = 0; base < deg; base += 64) {
        int j = base + lane;
        int b = -1;
        if (j < deg) b = nbr[start + j] >> BSHIFT;
        for (int bb = 0; bb < nb; ++bb) {
            unsigned long long m = __ballot(b == bb);
            if (lane == bb) myCount += __popcll(m);
        }
    }
    // exclusive scan over lanes -> bucket start offsets
    int incl = myCount;
    for (int d = 1; d < 64; d <<= 1) {
        int v = __shfl_up(incl, d);
        if (lane >= d) incl += v;
    }
    int excl = incl - myCount;
    if (lane <= nb) rbptr[row * (nb + 1) + lane] = start + excl; // lane nb: start+deg

    // pass 2: scatter into bucket-sorted pack, running cursor per bucket in lane regs
    int cursor = excl;
    float accq = 0.f;
    for (int base = 0; base < deg; base += 64) {
        int j = base + lane;
        int nb_i = 0; float bv = 0.f; int b = -1;
        if (j < deg) { nb_i = nbr[start + j]; bv = bl[start + j]; b = nb_i >> BSHIFT; }
        int pos = 0;
        for (int bb = 0; bb < nb; ++bb) {
            unsigned long long m = __ballot(b == bb);
            int basepos = __shfl(cursor, bb);
            if (b == bb) pos = basepos + __popcll(m & ((1ULL << lane) - 1ULL));
            if (lane == bb) cursor += __popcll(m);
        }
        if (j < deg) {
            unsigned q = quantize(bv);
            accq += (float)q;
            pack[start + pos] = (q << 18) | (unsigned)nb_i;
        }
    }
    #pragma unroll
    for (int off = 32; off > 0; off >>= 1) accq += __shfl_down(accq, off);
    if (lane == 0) {
        float r = 1.0f - accq * Q_INV;
        residual[row] = r;
        g1[row] = clip01(r);
    }
}

// Bucketed step: per bucket, stage 64KB gamma slice in LDS (coalesced, L2-hit),
// then 4-lane groups gather their rows' bucket edges from LDS.
__global__ __launch_bounds__(512) void step_lds(const float* __restrict__ gamma_in,
        const unsigned* __restrict__ pack, const int* __restrict__ rbptr,
        const float* __restrict__ residual, float* __restrict__ gamma_out,
        int n_part, int nb, int rpb) {
    __shared__ float s[BSIZE];
    int r0  = blockIdx.x * rpb;
    int g   = threadIdx.x >> 2;
    int sub = threadIdx.x & 3;
    int strideR = nb + 1;
    int rA = r0 + g, rB = r0 + g + 128, rC = r0 + g + 256, rD = r0 + g + 384;
    bool vA = (g       < rpb) && (rA < n_part);
    bool vB = (g + 128 < rpb) && (rB < n_part);
    bool vC = (g + 256 < rpb) && (rC < n_part);
    bool vD = (g + 384 < rpb) && (rD < n_part);
    float aA = 0.f, aB = 0.f, aC = 0.f, aD = 0.f;

    for (int b = 0; b < nb; ++b) {
        int sbase  = b << BSHIFT;
        int scount = min(BSIZE, n_part - sbase);
        __syncthreads();                     // previous phase done reading s
        for (int t = threadIdx.x * 4; t + 4 <= scount; t += 512 * 4)
            *(floatx4*)(s + t) = *(const floatx4*)(gamma_in + sbase + t);
        for (int t = (scount & ~3) + threadIdx.x; t < scount; t += 512)
            s[t] = gamma_in[sbase + t];
        __syncthreads();

#define ROWP(RV, VV, AA) if (VV) {                                        \
            int p0 = rbptr[(RV) * strideR + b];                           \
            int p1 = rbptr[(RV) * strideR + b + 1];                       \
            for (int j = p0 + sub; j < p1; j += 4) {                      \
                unsigned p = pack[j];                                     \
                AA += (float)(p >> 18) * s[(int)(p & NBR_MASK) - sbase];  \
            } }
        ROWP(rA, vA, aA)
        ROWP(rB, vB, aB)
        ROWP(rC, vC, aC)
        ROWP(rD, vD, aD)
#undef ROWP
    }
    aA += __shfl_down(aA, 2); aA += __shfl_down(aA, 1);
    aB += __shfl_down(aB, 2); aB += __shfl_down(aB, 1);
    aC += __shfl_down(aC, 2); aC += __shfl_down(aC, 1);
    aD += __shfl_down(aD, 2); aD += __shfl_down(aD, 1);
    if (sub == 0) {
        if (vA) gamma_out[rA] = clip01(aA * Q_INV + residual[rA]);
        if (vB) gamma_out[rB] = clip01(aB * Q_INV + residual[rB]);
        if (vC) gamma_out[rC] = clip01(aC * Q_INV + residual[rC]);
        if (vD) gamma_out[rD] = clip01(aD * Q_INV + residual[rD]);
    }
}

// ---------- fallback kernels (R4-proven path, no nt) ----------
__global__ void pack_kernel(const float* __restrict__ bl, const int* __restrict__ nbr,
                            unsigned* __restrict__ pack, int n_edges) {
    int i = (blockIdx.x * blockDim.x + threadIdx.x) * 4;
    if (i + 3 < n_edges) {
        float4 b = *(const float4*)(bl + i);
        int4   v = *(const int4*)(nbr + i);
        uint4  o;
        o.x = (quantize(b.x) << 18) | (unsigned)v.x;
        o.y = (quantize(b.y) << 18) | (unsigned)v.y;
        o.z = (quantize(b.z) << 18) | (unsigned)v.z;
        o.w = (quantize(b.w) << 18) | (unsigned)v.w;
        *(uint4*)(pack + i) = o;
    } else {
        for (; i < n_edges; ++i) pack[i] = (quantize(bl[i]) << 18) | (unsigned)nbr[i];
    }
}

__global__ void rowsum_g1(const unsigned* __restrict__ pack,
                          const int* __restrict__ row_ptr,
                          float* __restrict__ residual, float* __restrict__ g1,
                          int n_part) {
    int idx  = blockIdx.x * blockDim.x + threadIdx.x;
    int row  = idx >> 6;
    int lane = threadIdx.x & 63;
    if (row >= n_part) return;
    int start = row_ptr[row], end = row_ptr[row + 1];
    float acc = 0.0f;
    for (int e = start + lane; e < end; e += 64) acc += (float)(pack[e] >> 18);
    #pragma unroll
    for (int off = 32; off > 0; off >>= 1) acc += __shfl_down(acc, off);
    if (lane == 0) {
        float r = 1.0f - acc * Q_INV;
        residual[row] = r;
        g1[row] = clip01(r);
    }
}

__global__ __launch_bounds__(256) void step4(const float* __restrict__ gamma_in,
                                             const unsigned* __restrict__ pack,
                                             const int* __restrict__ row_ptr,
                                             const float* __restrict__ residual,
                                             float* __restrict__ gamma_out, int n_part) {
    int tid = blockIdx.x * 256 + threadIdx.x;
    int row = tid >> 2;
    int sub = tid & 3;
    if (row >= n_part) return;
    int start = row_ptr[row], end = row_ptr[row + 1];
    float acc = 0.0f;
    int abase = (start + 3) & ~3;
    {
        int j = start + sub;
        if (j < abase && j < end) {
            unsigned p = pack[j];
            acc += (float)(p >> 18) * gamma_in[p & NBR_MASK];
        }
    }
    int i = abase + sub * 4;
    #pragma unroll 2
    for (; i + 3 < end; i += 16) {
        uint4 p = *(const uint4*)(pack + i);
        float g0 = gamma_in[p.x & NBR_MASK];
        float g1v = gamma_in[p.y & NBR_MASK];
        float g2 = gamma_in[p.z & NBR_MASK];
        float g3 = gamma_in[p.w & NBR_MASK];
        acc += (float)(p.x >> 18) * g0 + (float)(p.y >> 18) * g1v
             + (float)(p.z >> 18) * g2 + (float)(p.w >> 18) * g3;
    }
    for (int j = i; j < end && j < i + 4; ++j) {
        unsigned p = pack[j];
        acc += (float)(p >> 18) * gamma_in[p & NBR_MASK];
    }
    acc += __shfl_down(acc, 2);
    acc += __shfl_down(acc, 1);
    if (sub == 0) {
        float g = acc * Q_INV + residual[row];
        gamma_out[row] = clip01(g);
    }
}

__global__ __launch_bounds__(256) void step4_raw(const float* __restrict__ gamma_in,
                                                 const float* __restrict__ bl,
                                                 const int* __restrict__ nbr,
                                                 const int* __restrict__ row_ptr,
                                                 const float* __restrict__ residual,
                                                 float* __restrict__ gamma_out, int n_part) {
    int tid = blockIdx.x * 256 + threadIdx.x;
    int row = tid >> 2;
    int sub = tid & 3;
    if (row >= n_part) return;
    int start = row_ptr[row], end = row_ptr[row + 1];
    float acc = 0.0f;
    for (int j = start + sub; j < end; j += 4)
        acc += bl[j] * gamma_in[nbr[j]];
    acc += __shfl_down(acc, 2);
    acc += __shfl_down(acc, 1);
    if (sub == 0) {
        float g = acc + residual[row];
        gamma_out[row] = clip01(g);
    }
}

__global__ void residual_raw(const float* __restrict__ bl,
                             const int* __restrict__ row_ptr,
                             float* __restrict__ residual, float* __restrict__ g1,
                             int n_part) {
    int idx  = blockIdx.x * blockDim.x + threadIdx.x;
    int row  = idx >> 6;
    int lane = threadIdx.x & 63;
    if (row >= n_part) return;
    int start = row_ptr[row], end = row_ptr[row + 1];
    float acc = 0.0f;
    for (int e = start + lane; e < end; e += 64) acc += bl[e];
    #pragma unroll
    for (int off = 32; off > 0; off >>= 1) acc += __shfl_down(acc, off);
    if (lane == 0) {
        float r = 1.0f - acc;
        residual[row] = r;
        g1[row] = clip01(r);
    }
}

extern "C" void kernel_launch(void* const* d_in, const int* in_sizes, int n_in,
                              void* d_out, int out_size, void* d_ws, size_t ws_size,
                              hipStream_t stream) {
    const float* bl  = (const float*)d_in[1];
    const int*   nbr = (const int*)d_in[2];
    const int*   seg = (const int*)d_in[3];
    const int n_part  = in_sizes[0];
    const int n_edges = in_sizes[1];
    const int horizon = 10;
    float* gout = (float*)d_out;
    const int BLK = 256;

    auto align256 = [](size_t x) { return (x + 255) & ~(size_t)255; };
    char* ws = (char*)d_ws;
    size_t off = 0;
    int* row_ptr = (int*)(ws + off);      off += align256((size_t)(n_part + 1) * 4);
    float* residual = (float*)(ws + off); off += align256((size_t)n_part * 4);
    float* bufX = (float*)(ws + off);     off += align256((size_t)n_part * 4);
    float* bufY = (float*)(ws + off);     off += align256((size_t)n_part * 4);
    size_t off_base = off;

    int nb = (n_part + BSIZE - 1) >> BSHIFT;
    // bucket layout: rbptr then pack
    size_t rbptr_off = off_base;
    size_t pack_b_off = rbptr_off + align256((size_t)n_part * (size_t)(nb + 1) * 4);
    size_t need_bucket = pack_b_off + align256((size_t)(n_edges + 4) * 4);
    // packed (fallback) layout: pack right after bufY
    size_t pack_p_off = off_base;
    size_t need_packed = pack_p_off + align256((size_t)(n_edges + 4) * 4);

    bool use_bucket = (nb <= 16) && (ws_size >= need_bucket);
    bool use_packed = ws_size >= need_packed;

    build_rowptr<<<dim3((n_edges + BLK - 1) / BLK), dim3(BLK), 0, stream>>>(
        seg, row_ptr, n_edges, n_part);

    int wave_row_blocks = (n_part * 64 + BLK - 1) / BLK;
    int step_blocks     = (n_part * 4  + BLK - 1) / BLK;

    if (use_bucket) {
        int* rbptr = (int*)(ws + rbptr_off);
        unsigned* pack = (unsigned*)(ws + pack_b_off);
        sortpack<<<dim3(wave_row_blocks), dim3(BLK), 0, stream>>>(
            bl, nbr, row_ptr, pack, rbptr, residual, bufX, n_part, nb);
        int rpb = (n_part + 511) / 512;
        int grid = (n_part + rpb - 1) / rpb;   // == 512 for n_part in (511*rpb, 512*rpb]
        const float* cur = bufX;               // gamma1 = clip(residual), gamma0 == 0
        for (int t = 2; t <= horizon; ++t) {
            float* dst = (t == horizon) ? gout : ((t & 1) ? bufX : bufY);
            step_lds<<<dim3(grid), dim3(512), 0, stream>>>(
                cur, pack, rbptr, residual, dst, n_part, nb, rpb);
            cur = dst;
        }
        if (cur != gout)
            (void)hipMemcpyAsync(gout, cur, (size_t)n_part * 4, hipMemcpyDeviceToDevice, stream);
    } else if (use_packed) {
        unsigned* pack = (unsigned*)(ws + pack_p_off);
        int pack_threads = (n_edges + 3) / 4;
        pack_kernel<<<dim3((pack_threads + BLK - 1) / BLK), dim3(BLK), 0, stream>>>(
            bl, nbr, pack, n_edges);
        rowsum_g1<<<dim3(wave_row_blocks), dim3(BLK), 0, stream>>>(
            pack, row_ptr, residual, bufX, n_part);
        const float* cur = bufX;
        for (int t = 2; t <= horizon; ++t) {
            float* dst = (t == horizon) ? gout : ((t & 1) ? bufX : bufY);
            step4<<<dim3(step_blocks), dim3(BLK), 0, stream>>>(
                cur, pack, row_ptr, residual, dst, n_part);
            cur = dst;
        }
        if (cur != gout)
            (void)hipMemcpyAsync(gout, cur, (size_t)n_part * 4, hipMemcpyDeviceToDevice, stream);
    } else {
        residual_raw<<<dim3(wave_row_blocks), dim3(BLK), 0, stream>>>(
            bl, row_ptr, residual, bufX, n_part);
        const float* cur = bufX;
        for (int t = 2; t <= horizon; ++t) {
            float* dst = (t == horizon) ? gout : ((t & 1) ? bufX : bufY);
            step4_raw<<<dim3(step_blocks), dim3(BLK), 0, stream>>>(
                cur, bl, nbr, row_ptr, residual, dst, n_part);
            cur = dst;
        }
        if (cur != gout)
            (void)hipMemcpyAsync(gout, cur, (size_t)n_part * 4, hipMemcpyDeviceToDevice, stream);
    }
}

// Round 5
// 1270.657 us; speedup vs baseline: 1.2510x; 1.2510x over previous
//
#include <hip/hip_runtime.h>

// gamma_{t+1}[j] = clip(sum_e w[e]*gamma_t[nbr[e]] + residual[j], 0, 1), 10 steps.
// R9: bucket-MAJOR bucketed-LDS SpMV.
// R8 post-mortem: row-major bucket-sorted pack made the step's pack reads 40B
// scattered segments (2-4x overfetch, serial HBM-latency chains) -> 143us/step.
// Fix: edges stored bucket-major (bucket b's edges for all rows, row order).
// Per phase, consecutive groups read consecutive memory -> fully linear stream.
// Gathers from a 64KB LDS gamma slice (no L1-MSHR cap). Prep: counts (ballots)
// -> flat exclusive scan (3 small kernels) -> ballot-rank scatter (+residual).
// Edge pack u32: bits[27:14] = round(bl*2^21) (bl < 2^-7), bits[13:0] = nbr&0x3FFF.

#define BSHIFT 14
#define BSIZE  16384                   // floats per slice (64 KB LDS)
#define LMASK  0x3FFFu
#define Q_SCALE 2097152.0f            // 2^21
#define Q_INV   4.76837158203125e-07f // 2^-21

typedef float floatx4 __attribute__((ext_vector_type(4)));
typedef int   intx4   __attribute__((ext_vector_type(4)));

__device__ __forceinline__ unsigned quantize(float b) {
    unsigned q = (unsigned)(b * Q_SCALE + 0.5f);
    return q > 16383u ? 16383u : q;
}
__device__ __forceinline__ float clip01(float x) { return fminf(fmaxf(x, 0.f), 1.f); }

// row_ptr[j] = first edge index with seg >= j.
__global__ void build_rowptr(const int* __restrict__ seg, int* __restrict__ row_ptr,
                             int n_edges, int n_part) {
    int e = blockIdx.x * blockDim.x + threadIdx.x;
    if (e >= n_edges) return;
    int s = seg[e];
    int sprev = (e == 0) ? -1 : seg[e - 1];
    for (int j = sprev + 1; j <= s; ++j) row_ptr[j] = e;
    if (e == n_edges - 1)
        for (int j = s + 1; j <= n_part; ++j) row_ptr[j] = n_edges;
}

// P1: one wave per row -> per-bucket counts into OFF[b*n_part + row].
__global__ __launch_bounds__(256) void count_buckets(const int* __restrict__ nbr,
        const int* __restrict__ row_ptr, int* __restrict__ OFF,
        int n_part, int nb) {
    int row  = (blockIdx.x * 256 + threadIdx.x) >> 6;
    int lane = threadIdx.x & 63;
    if (row >= n_part) return;
    int start = row_ptr[row], deg = row_ptr[row + 1] - start;
    int myCount = 0;
    for (int base = 0; base < deg; base += 64) {
        int j = base + lane;
        int b = (j < deg) ? (nbr[start + j] >> BSHIFT) : -1;
        for (int bb = 0; bb < nb; ++bb) {
            unsigned long long m = __ballot(b == bb);
            if (lane == bb) myCount += __popcll(m);
        }
    }
    if (lane < nb) OFF[(size_t)lane * n_part + row] = myCount;
}

// P2a: per-chunk (8192 cells) sums.
__global__ __launch_bounds__(1024) void scan_part(const int* __restrict__ OFF,
        int* __restrict__ part, int cells) {
    __shared__ int wl[16];
    int base = blockIdx.x * 8192 + threadIdx.x * 8;
    int s = 0;
    if (base + 8 <= cells) {
        intx4 a = *(const intx4*)(OFF + base);
        intx4 b = *(const intx4*)(OFF + base + 4);
        s = a.x + a.y + a.z + a.w + b.x + b.y + b.z + b.w;
    } else {
        for (int k = 0; k < 8; ++k) if (base + k < cells) s += OFF[base + k];
    }
    int incl = s;
    #pragma unroll
    for (int d = 1; d < 64; d <<= 1) { int t = __shfl_up(incl, d); if ((threadIdx.x & 63) >= d) incl += t; }
    if ((threadIdx.x & 63) == 63) wl[threadIdx.x >> 6] = incl;
    __syncthreads();
    if (threadIdx.x == 0) {
        int tot = 0;
        for (int w = 0; w < 16; ++w) tot += wl[w];
        part[blockIdx.x] = tot;
    }
}

// P2b: exclusive scan of part[0..SB) in one block; also OFF[cells] = n_edges.
__global__ __launch_bounds__(1024) void scan_top(int* __restrict__ part,
        int* __restrict__ OFF, int SB, int cells, int n_edges) {
    __shared__ int a[1024];
    int v = (threadIdx.x < SB) ? part[threadIdx.x] : 0;
    a[threadIdx.x] = v;
    __syncthreads();
    for (int off = 1; off < 1024; off <<= 1) {
        int t = (threadIdx.x >= off) ? a[threadIdx.x - off] : 0;
        __syncthreads();
        a[threadIdx.x] += t;
        __syncthreads();
    }
    if (threadIdx.x < SB) part[threadIdx.x] = a[threadIdx.x] - v;
    if (threadIdx.x == 0) OFF[cells] = n_edges;
}

// P2c: in-place exclusive scan of each chunk, offset by part[blk].
__global__ __launch_bounds__(1024) void scan_apply(int* __restrict__ OFF,
        const int* __restrict__ part, int cells) {
    __shared__ int wl[16];
    int base = blockIdx.x * 8192 + threadIdx.x * 8;
    int v[8]; int s = 0;
    #pragma unroll
    for (int k = 0; k < 8; ++k) {
        v[k] = (base + k < cells) ? OFF[base + k] : 0;
        s += v[k];
    }
    int lane = threadIdx.x & 63, wid = threadIdx.x >> 6;
    int incl = s;
    #pragma unroll
    for (int d = 1; d < 64; d <<= 1) { int t = __shfl_up(incl, d); if (lane >= d) incl += t; }
    if (lane == 63) wl[wid] = incl;
    __syncthreads();
    if (threadIdx.x == 0) {
        int run = 0;
        for (int w = 0; w < 16; ++w) { int t = wl[w]; wl[w] = run; run += t; }
    }
    __syncthreads();
    int run = part[blockIdx.x] + wl[wid] + (incl - s);
    #pragma unroll
    for (int k = 0; k < 8; ++k) {
        if (base + k < cells) OFF[base + k] = run;
        run += v[k];
    }
}

// P3: one wave per row: ballot-rank scatter into bucket-major pack + residual/g1.
__global__ __launch_bounds__(256) void scatter_pack(const float* __restrict__ bl,
        const int* __restrict__ nbr, const int* __restrict__ row_ptr,
        const int* __restrict__ OFF, unsigned* __restrict__ pack,
        float* __restrict__ residual, float* __restrict__ g1,
        int n_part, int nb) {
    int row  = (blockIdx.x * 256 + threadIdx.x) >> 6;
    int lane = threadIdx.x & 63;
    if (row >= n_part) return;
    int start = row_ptr[row], deg = row_ptr[row + 1] - start;
    int cur = (lane < nb) ? OFF[(size_t)lane * n_part + row] : 0;
    float accq = 0.f;
    for (int base = 0; base < deg; base += 64) {
        int j = base + lane;
        int nb_i = 0; float bv = 0.f; int b = -1;
        if (j < deg) { nb_i = nbr[start + j]; bv = bl[start + j]; b = nb_i >> BSHIFT; }
        int pos = 0;
        for (int bb = 0; bb < nb; ++bb) {
            unsigned long long m = __ballot(b == bb);
            int basep = __shfl(cur, bb);
            if (b == bb) pos = basep + __popcll(m & ((1ULL << lane) - 1ULL));
            if (lane == bb) cur += __popcll(m);
        }
        if (j < deg) {
            unsigned q = quantize(bv);
            accq += (float)q;
            pack[pos] = (q << 14) | ((unsigned)nb_i & LMASK);
        }
    }
    #pragma unroll
    for (int off = 32; off > 0; off >>= 1) accq += __shfl_down(accq, off);
    if (lane == 0) {
        float r = 1.0f - accq * Q_INV;
        residual[row] = r;
        g1[row] = clip01(r);
    }
}

// Step: per bucket phase, stage 64KB gamma slice in LDS, then each 4-lane group
// walks its rows' bucket-b segments. Bucket-major pack => linear streaming reads.
__global__ __launch_bounds__(512) void step_bm(const float* __restrict__ gamma_in,
        const unsigned* __restrict__ pack, const int* __restrict__ OFF,
        const float* __restrict__ residual, float* __restrict__ gamma_out,
        int n_part, int nb, int rpb) {
    __shared__ float s[BSIZE];
    int r0  = blockIdx.x * rpb;
    int g   = threadIdx.x >> 2;
    int sub = threadIdx.x & 3;
    int rA = r0 + g, rB = r0 + g + 128, rC = r0 + g + 256, rD = r0 + g + 384;
    bool vA = (g       < rpb) && (rA < n_part);
    bool vB = (g + 128 < rpb) && (rB < n_part);
    bool vC = (g + 256 < rpb) && (rC < n_part);
    bool vD = (g + 384 < rpb) && (rD < n_part);
    float aA = 0.f, aB = 0.f, aC = 0.f, aD = 0.f;

    for (int b = 0; b < nb; ++b) {
        int sbase  = b << BSHIFT;
        int scount = min(BSIZE, n_part - sbase);
        __syncthreads();                      // prior phase done reading s
        for (int t = threadIdx.x * 4; t + 4 <= scount; t += 2048)
            *(floatx4*)(s + t) = *(const floatx4*)(gamma_in + sbase + t);
        for (int t = (scount & ~3) + threadIdx.x; t < scount; t += 512)
            s[t] = gamma_in[sbase + t];
        __syncthreads();

        int bn = b * n_part;
        // issue all segment-pointer loads up front (independent -> overlapped)
        int p0A = 0, p1A = 0, p0B = 0, p1B = 0, p0C = 0, p1C = 0, p0D = 0, p1D = 0;
        if (vA) { p0A = OFF[bn + rA]; p1A = OFF[bn + rA + 1]; }
        if (vB) { p0B = OFF[bn + rB]; p1B = OFF[bn + rB + 1]; }
        if (vC) { p0C = OFF[bn + rC]; p1C = OFF[bn + rC + 1]; }
        if (vD) { p0D = OFF[bn + rD]; p1D = OFF[bn + rD + 1]; }
        for (int j = p0A + sub; j < p1A; j += 4) {
            unsigned p = pack[j]; aA += (float)(p >> 14) * s[p & LMASK];
        }
        for (int j = p0B + sub; j < p1B; j += 4) {
            unsigned p = pack[j]; aB += (float)(p >> 14) * s[p & LMASK];
        }
        for (int j = p0C + sub; j < p1C; j += 4) {
            unsigned p = pack[j]; aC += (float)(p >> 14) * s[p & LMASK];
        }
        for (int j = p0D + sub; j < p1D; j += 4) {
            unsigned p = pack[j]; aD += (float)(p >> 14) * s[p & LMASK];
        }
    }
    aA += __shfl_down(aA, 2); aA += __shfl_down(aA, 1);
    aB += __shfl_down(aB, 2); aB += __shfl_down(aB, 1);
    aC += __shfl_down(aC, 2); aC += __shfl_down(aC, 1);
    aD += __shfl_down(aD, 2); aD += __shfl_down(aD, 1);
    if (sub == 0) {
        if (vA) gamma_out[rA] = clip01(aA * Q_INV + residual[rA]);
        if (vB) gamma_out[rB] = clip01(aB * Q_INV + residual[rB]);
        if (vC) gamma_out[rC] = clip01(aC * Q_INV + residual[rC]);
        if (vD) gamma_out[rD] = clip01(aD * Q_INV + residual[rD]);
    }
}

// ---------- fallback kernels (R4-proven path) ----------
#define NBR_MASK 0x3FFFFu
__global__ void pack_kernel(const float* __restrict__ bl, const int* __restrict__ nbr,
                            unsigned* __restrict__ pack, int n_edges) {
    int i = (blockIdx.x * blockDim.x + threadIdx.x) * 4;
    if (i + 3 < n_edges) {
        float4 b = *(const float4*)(bl + i);
        int4   v = *(const int4*)(nbr + i);
        uint4  o;
        o.x = (quantize(b.x) << 18) | (unsigned)v.x;
        o.y = (quantize(b.y) << 18) | (unsigned)v.y;
        o.z = (quantize(b.z) << 18) | (unsigned)v.z;
        o.w = (quantize(b.w) << 18) | (unsigned)v.w;
        *(uint4*)(pack + i) = o;
    } else {
        for (; i < n_edges; ++i) pack[i] = (quantize(bl[i]) << 18) | (unsigned)nbr[i];
    }
}

__global__ void rowsum_g1(const unsigned* __restrict__ pack,
                          const int* __restrict__ row_ptr,
                          float* __restrict__ residual, float* __restrict__ g1,
                          int n_part) {
    int idx  = blockIdx.x * blockDim.x + threadIdx.x;
    int row  = idx >> 6;
    int lane = threadIdx.x & 63;
    if (row >= n_part) return;
    int start = row_ptr[row], end = row_ptr[row + 1];
    float acc = 0.0f;
    for (int e = start + lane; e < end; e += 64) acc += (float)(pack[e] >> 18);
    #pragma unroll
    for (int off = 32; off > 0; off >>= 1) acc += __shfl_down(acc, off);
    if (lane == 0) {
        float r = 1.0f - acc * Q_INV;
        residual[row] = r;
        g1[row] = clip01(r);
    }
}

__global__ __launch_bounds__(256) void step4(const float* __restrict__ gamma_in,
                                             const unsigned* __restrict__ pack,
                                             const int* __restrict__ row_ptr,
                                             const float* __restrict__ residual,
                                             float* __restrict__ gamma_out, int n_part) {
    int tid = blockIdx.x * 256 + threadIdx.x;
    int row = tid >> 2;
    int sub = tid & 3;
    if (row >= n_part) return;
    int start = row_ptr[row], end = row_ptr[row + 1];
    float acc = 0.0f;
    int abase = (start + 3) & ~3;
    {
        int j = start + sub;
        if (j < abase && j < end) {
            unsigned p = pack[j];
            acc += (float)(p >> 18) * gamma_in[p & NBR_MASK];
        }
    }
    int i = abase + sub * 4;
    #pragma unroll 2
    for (; i + 3 < end; i += 16) {
        uint4 p = *(const uint4*)(pack + i);
        float g0 = gamma_in[p.x & NBR_MASK];
        float g1v = gamma_in[p.y & NBR_MASK];
        float g2 = gamma_in[p.z & NBR_MASK];
        float g3 = gamma_in[p.w & NBR_MASK];
        acc += (float)(p.x >> 18) * g0 + (float)(p.y >> 18) * g1v
             + (float)(p.z >> 18) * g2 + (float)(p.w >> 18) * g3;
    }
    for (int j = i; j < end && j < i + 4; ++j) {
        unsigned p = pack[j];
        acc += (float)(p >> 18) * gamma_in[p & NBR_MASK];
    }
    acc += __shfl_down(acc, 2);
    acc += __shfl_down(acc, 1);
    if (sub == 0) {
        float g = acc * Q_INV + residual[row];
        gamma_out[row] = clip01(g);
    }
}

__global__ __launch_bounds__(256) void step4_raw(const float* __restrict__ gamma_in,
                                                 const float* __restrict__ bl,
                                                 const int* __restrict__ nbr,
                                                 const int* __restrict__ row_ptr,
                                                 const float* __restrict__ residual,
                                                 float* __restrict__ gamma_out, int n_part) {
    int tid = blockIdx.x * 256 + threadIdx.x;
    int row = tid >> 2;
    int sub = tid & 3;
    if (row >= n_part) return;
    int start = row_ptr[row], end = row_ptr[row + 1];
    float acc = 0.0f;
    for (int j = start + sub; j < end; j += 4)
        acc += bl[j] * gamma_in[nbr[j]];
    acc += __shfl_down(acc, 2);
    acc += __shfl_down(acc, 1);
    if (sub == 0) {
        float g = acc + residual[row];
        gamma_out[row] = clip01(g);
    }
}

__global__ void residual_raw(const float* __restrict__ bl,
                             const int* __restrict__ row_ptr,
                             float* __restrict__ residual, float* __restrict__ g1,
                             int n_part) {
    int idx  = blockIdx.x * blockDim.x + threadIdx.x;
    int row  = idx >> 6;
    int lane = threadIdx.x & 63;
    if (row >= n_part) return;
    int start = row_ptr[row], end = row_ptr[row + 1];
    float acc = 0.0f;
    for (int e = start + lane; e < end; e += 64) acc += bl[e];
    #pragma unroll
    for (int off = 32; off > 0; off >>= 1) acc += __shfl_down(acc, off);
    if (lane == 0) {
        float r = 1.0f - acc;
        residual[row] = r;
        g1[row] = clip01(r);
    }
}

extern "C" void kernel_launch(void* const* d_in, const int* in_sizes, int n_in,
                              void* d_out, int out_size, void* d_ws, size_t ws_size,
                              hipStream_t stream) {
    const float* bl  = (const float*)d_in[1];
    const int*   nbr = (const int*)d_in[2];
    const int*   seg = (const int*)d_in[3];
    const int n_part  = in_sizes[0];
    const int n_edges = in_sizes[1];
    const int horizon = 10;
    float* gout = (float*)d_out;
    const int BLK = 256;

    auto align256 = [](size_t x) { return (x + 255) & ~(size_t)255; };
    char* ws = (char*)d_ws;
    size_t off = 0;
    int* row_ptr = (int*)(ws + off);      off += align256((size_t)(n_part + 1) * 4);
    float* residual = (float*)(ws + off); off += align256((size_t)n_part * 4);
    float* bufX = (float*)(ws + off);     off += align256((size_t)n_part * 4);
    float* bufY = (float*)(ws + off);     off += align256((size_t)n_part * 4);
    size_t off_base = off;

    int nb = (n_part + BSIZE - 1) >> BSHIFT;
    int cells = nb * n_part;
    int SB = (cells + 8191) / 8192;

    // bucket-major layout: OFF (cells+1), part (<=1024), pack (n_edges)
    size_t off_off  = off_base;
    size_t part_off = off_off + align256(((size_t)cells + 1) * 4);
    size_t packb_off = part_off + align256(1024 * 4);
    size_t need_bm = packb_off + align256((size_t)(n_edges + 4) * 4);
    // fallback packed layout
    size_t packp_off = off_base;
    size_t need_packed = packp_off + align256((size_t)(n_edges + 4) * 4);

    bool use_bm = (nb >= 1) && (nb <= 32) && (SB <= 1024) && (ws_size >= need_bm);
    bool use_packed = ws_size >= need_packed;

    build_rowptr<<<dim3((n_edges + BLK - 1) / BLK), dim3(BLK), 0, stream>>>(
        seg, row_ptr, n_edges, n_part);

    int wave_row_blocks = (n_part * 64 + BLK - 1) / BLK;
    int step_blocks     = (n_part * 4  + BLK - 1) / BLK;

    if (use_bm) {
        int* OFF = (int*)(ws + off_off);
        int* part = (int*)(ws + part_off);
        unsigned* pack = (unsigned*)(ws + packb_off);
        count_buckets<<<dim3(wave_row_blocks), dim3(BLK), 0, stream>>>(
            nbr, row_ptr, OFF, n_part, nb);
        scan_part<<<dim3(SB), dim3(1024), 0, stream>>>(OFF, part, cells);
        scan_top<<<dim3(1), dim3(1024), 0, stream>>>(part, OFF, SB, cells, n_edges);
        scan_apply<<<dim3(SB), dim3(1024), 0, stream>>>(OFF, part, cells);
        scatter_pack<<<dim3(wave_row_blocks), dim3(BLK), 0, stream>>>(
            bl, nbr, row_ptr, OFF, pack, residual, bufX, n_part, nb);
        int rpb = (n_part + 511) / 512;
        int grid = (n_part + rpb - 1) / rpb;
        const float* cur = bufX;               // gamma1 = clip(residual), gamma0 == 0
        for (int t = 2; t <= horizon; ++t) {
            float* dst = (t == horizon) ? gout : ((t & 1) ? bufX : bufY);
            step_bm<<<dim3(grid), dim3(512), 0, stream>>>(
                cur, pack, OFF, residual, dst, n_part, nb, rpb);
            cur = dst;
        }
        if (cur != gout)
            (void)hipMemcpyAsync(gout, cur, (size_t)n_part * 4, hipMemcpyDeviceToDevice, stream);
    } else if (use_packed) {
        unsigned* pack = (unsigned*)(ws + packp_off);
        int pack_threads = (n_edges + 3) / 4;
        pack_kernel<<<dim3((pack_threads + BLK - 1) / BLK), dim3(BLK), 0, stream>>>(
            bl, nbr, pack, n_edges);
        rowsum_g1<<<dim3(wave_row_blocks), dim3(BLK), 0, stream>>>(
            pack, row_ptr, residual, bufX, n_part);
        const float* cur = bufX;
        for (int t = 2; t <= horizon; ++t) {
            float* dst = (t == horizon) ? gout : ((t & 1) ? bufX : bufY);
            step4<<<dim3(step_blocks), dim3(BLK), 0, stream>>>(
                cur, pack, row_ptr, residual, dst, n_part);
            cur = dst;
        }
        if (cur != gout)
            (void)hipMemcpyAsync(gout, cur, (size_t)n_part * 4, hipMemcpyDeviceToDevice, stream);
    } else {
        residual_raw<<<dim3(wave_row_blocks), dim3(BLK), 0, stream>>>(
            bl, row_ptr, residual, bufX, n_part);
        const float* cur = bufX;
        for (int t = 2; t <= horizon; ++t) {
            float* dst = (t == horizon) ? gout : ((t & 1) ? bufX : bufY);
            step4_raw<<<dim3(step_blocks), dim3(BLK), 0, stream>>>(
                cur, bl, nbr, row_ptr, residual, dst, n_part);
            cur = dst;
        }
        if (cur != gout)
            (void)hipMemcpyAsync(gout, cur, (size_t)n_part * 4, hipMemcpyDeviceToDevice, stream);
    }
}

// Round 6
// 1093.743 us; speedup vs baseline: 1.4534x; 1.1618x over previous
//
#include <hip/hip_runtime.h>

// gamma_{t+1}[j] = clip(sum_e w[e]*gamma_t[nbr[e]] + residual[j], 0, 1), 10 steps.
// R10: bucket-major LDS SpMV, round 2.
//  - prep: 13-iter ballot loops replaced by 4-ballot class-mask rank + per-wave
//    LDS cursor atomics (O(4) instead of O(nb) per 64-edge chunk). Pack layout
//    bit-identical to R9 (rank is lane-ordered).
//  - step_db: 1024 thr, 2x64KB double-buffered LDS slices, grid=256 (1 block/CU,
//    16 waves/CU); next slice staged global->reg BEFORE the gather phase and
//    ds_written after the barrier -> slice-load latency hidden under gathers.
// Edge pack u32: bits[27:14] = round(bl*2^21) (bl < 2^-7), bits[13:0] = nbr&0x3FFF.

#define BSHIFT 14
#define BSIZE  16384                   // floats per slice (64 KB)
#define LMASK  0x3FFFu
#define Q_SCALE 2097152.0f            // 2^21
#define Q_INV   4.76837158203125e-07f // 2^-21

typedef float floatx4 __attribute__((ext_vector_type(4)));
typedef int   intx4   __attribute__((ext_vector_type(4)));

__device__ __forceinline__ unsigned quantize(float b) {
    unsigned q = (unsigned)(b * Q_SCALE + 0.5f);
    return q > 16383u ? 16383u : q;
}
__device__ __forceinline__ float clip01(float x) { return fminf(fmaxf(x, 0.f), 1.f); }

// class mask: lanes whose 4-bit bucket id equals mine (4 ballots).
__device__ __forceinline__ unsigned long long class_mask(int b) {
    unsigned long long m = ~0ULL;
    #pragma unroll
    for (int k = 0; k < 4; ++k) {
        unsigned long long bb = __ballot((b >> k) & 1);
        m &= ((b >> k) & 1) ? bb : ~bb;
    }
    return m;
}

// row_ptr[j] = first edge index with seg >= j.
__global__ void build_rowptr(const int* __restrict__ seg, int* __restrict__ row_ptr,
                             int n_edges, int n_part) {
    int e = blockIdx.x * blockDim.x + threadIdx.x;
    if (e >= n_edges) return;
    int s = seg[e];
    int sprev = (e == 0) ? -1 : seg[e - 1];
    for (int j = sprev + 1; j <= s; ++j) row_ptr[j] = e;
    if (e == n_edges - 1)
        for (int j = s + 1; j <= n_part; ++j) row_ptr[j] = n_edges;
}

// P1: one wave per row -> per-bucket counts into OFF[b*n_part + row].
__global__ __launch_bounds__(256) void count_buckets(const int* __restrict__ nbr,
        const int* __restrict__ row_ptr, int* __restrict__ OFF,
        int n_part, int nb) {
    __shared__ int cnt[4][16];
    int wid  = threadIdx.x >> 6;
    int lane = threadIdx.x & 63;
    int row  = (blockIdx.x * 256 + threadIdx.x) >> 6;
    bool rv  = row < n_part;
    if (lane < 16) cnt[wid][lane] = 0;
    __syncthreads();
    if (rv) {
        int start = row_ptr[row], deg = row_ptr[row + 1] - start;
        for (int base = 0; base < deg; base += 64) {
            int j = base + lane;
            int b = (j < deg) ? (nbr[start + j] >> BSHIFT) : 15;
            unsigned long long m = class_mask(b);
            int rank = __popcll(m & ((1ULL << lane) - 1ULL));
            if (rank == 0 && b != 15) atomicAdd(&cnt[wid][b], __popcll(m));
        }
    }
    __syncthreads();
    if (rv && lane < nb) OFF[(size_t)lane * n_part + row] = cnt[wid][lane];
}

// P2a: per-chunk (8192 cells) sums.
__global__ __launch_bounds__(1024) void scan_part(const int* __restrict__ OFF,
        int* __restrict__ part, int cells) {
    __shared__ int wl[16];
    int base = blockIdx.x * 8192 + threadIdx.x * 8;
    int s = 0;
    if (base + 8 <= cells) {
        intx4 a = *(const intx4*)(OFF + base);
        intx4 b = *(const intx4*)(OFF + base + 4);
        s = a.x + a.y + a.z + a.w + b.x + b.y + b.z + b.w;
    } else {
        for (int k = 0; k < 8; ++k) if (base + k < cells) s += OFF[base + k];
    }
    int incl = s;
    #pragma unroll
    for (int d = 1; d < 64; d <<= 1) { int t = __shfl_up(incl, d); if ((threadIdx.x & 63) >= d) incl += t; }
    if ((threadIdx.x & 63) == 63) wl[threadIdx.x >> 6] = incl;
    __syncthreads();
    if (threadIdx.x == 0) {
        int tot = 0;
        for (int w = 0; w < 16; ++w) tot += wl[w];
        part[blockIdx.x] = tot;
    }
}

// P2b: exclusive scan of part[0..SB) in one block; also OFF[cells] = n_edges.
__global__ __launch_bounds__(1024) void scan_top(int* __restrict__ part,
        int* __restrict__ OFF, int SB, int cells, int n_edges) {
    __shared__ int a[1024];
    int v = (threadIdx.x < SB) ? part[threadIdx.x] : 0;
    a[threadIdx.x] = v;
    __syncthreads();
    for (int off = 1; off < 1024; off <<= 1) {
        int t = (threadIdx.x >= off) ? a[threadIdx.x - off] : 0;
        __syncthreads();
        a[threadIdx.x] += t;
        __syncthreads();
    }
    if (threadIdx.x < SB) part[threadIdx.x] = a[threadIdx.x] - v;
    if (threadIdx.x == 0) OFF[cells] = n_edges;
}

// P2c: in-place exclusive scan of each chunk, offset by part[blk].
__global__ __launch_bounds__(1024) void scan_apply(int* __restrict__ OFF,
        const int* __restrict__ part, int cells) {
    __shared__ int wl[16];
    int base = blockIdx.x * 8192 + threadIdx.x * 8;
    int v[8]; int s = 0;
    #pragma unroll
    for (int k = 0; k < 8; ++k) {
        v[k] = (base + k < cells) ? OFF[base + k] : 0;
        s += v[k];
    }
    int lane = threadIdx.x & 63, wid = threadIdx.x >> 6;
    int incl = s;
    #pragma unroll
    for (int d = 1; d < 64; d <<= 1) { int t = __shfl_up(incl, d); if (lane >= d) incl += t; }
    if (lane == 63) wl[wid] = incl;
    __syncthreads();
    if (threadIdx.x == 0) {
        int run = 0;
        for (int w = 0; w < 16; ++w) { int t = wl[w]; wl[w] = run; run += t; }
    }
    __syncthreads();
    int run = part[blockIdx.x] + wl[wid] + (incl - s);
    #pragma unroll
    for (int k = 0; k < 8; ++k) {
        if (base + k < cells) OFF[base + k] = run;
        run += v[k];
    }
}

// P3: one wave per row: class-mask rank scatter into bucket-major pack + residual/g1.
__global__ __launch_bounds__(256) void scatter_pack(const float* __restrict__ bl,
        const int* __restrict__ nbr, const int* __restrict__ row_ptr,
        const int* __restrict__ OFF, unsigned* __restrict__ pack,
        float* __restrict__ residual, float* __restrict__ g1,
        int n_part, int nb) {
    __shared__ int cur[4][16];
    int wid  = threadIdx.x >> 6;
    int lane = threadIdx.x & 63;
    int row  = (blockIdx.x * 256 + threadIdx.x) >> 6;
    bool rv  = row < n_part;
    if (lane < 16) cur[wid][lane] = (rv && lane < nb) ? OFF[(size_t)lane * n_part + row] : 0;
    __syncthreads();
    if (rv) {
        int start = row_ptr[row], deg = row_ptr[row + 1] - start;
        float accq = 0.f;
        for (int base = 0; base < deg; base += 64) {
            int j = base + lane;
            int nb_i = 0; float bv = 0.f; int b = 15;
            if (j < deg) { nb_i = nbr[start + j]; bv = bl[start + j]; b = nb_i >> BSHIFT; }
            unsigned long long m = class_mask(b);
            int rank = __popcll(m & ((1ULL << lane) - 1ULL));
            int leader_lane = (int)__ffsll((long long)m) - 1;
            int old = 0;
            if (rank == 0 && b != 15) old = atomicAdd(&cur[wid][b], __popcll(m));
            int basep = __shfl(old, leader_lane);
            if (b != 15) {
                unsigned q = quantize(bv);
                accq += (float)q;
                pack[basep + rank] = (q << 14) | ((unsigned)nb_i & LMASK);
            }
        }
        #pragma unroll
        for (int off = 32; off > 0; off >>= 1) accq += __shfl_down(accq, off);
        if (lane == 0) {
            float r = 1.0f - accq * Q_INV;
            residual[row] = r;
            g1[row] = clip01(r);
        }
    }
}

// Step: double-buffered 64KB slices; next slice staged global->reg before the
// gather phase, ds_written after the barrier (slice-load latency hidden).
__global__ __launch_bounds__(1024) void step_db(const float* __restrict__ gamma_in,
        const unsigned* __restrict__ pack, const int* __restrict__ OFF,
        const float* __restrict__ residual, float* __restrict__ gamma_out,
        int n_part, int nb, int rpb) {
    __shared__ float s[2][BSIZE];
    int g   = threadIdx.x >> 2;
    int sub = threadIdx.x & 3;
    int r0  = blockIdx.x * rpb;
    int rA = r0 + g, rB = r0 + g + 256, rC = r0 + g + 512, rD = r0 + g + 768;
    bool vA = (g       < rpb) && (rA < n_part);
    bool vB = (g + 256 < rpb) && (rB < n_part);
    bool vC = (g + 512 < rpb) && (rC < n_part);
    bool vD = (g + 768 < rpb) && (rD < n_part);
    float aA = 0.f, aB = 0.f, aC = 0.f, aD = 0.f;

    floatx4 st[4];
    // prologue: stage slice 0 and write to buf 0
    {
        int scount = min(BSIZE, n_part);
        #pragma unroll
        for (int i = 0; i < 4; ++i) {
            int fi = (threadIdx.x + 1024 * i) * 4;
            if (fi + 3 < scount) st[i] = *(const floatx4*)(gamma_in + fi);
            else {
                floatx4 z = {0.f, 0.f, 0.f, 0.f};
                for (int e = 0; e < 4; ++e) if (fi + e < scount) z[e] = gamma_in[fi + e];
                st[i] = z;
            }
        }
        #pragma unroll
        for (int i = 0; i < 4; ++i)
            *(floatx4*)(&s[0][(threadIdx.x + 1024 * i) * 4]) = st[i];
    }
    __syncthreads();

    for (int b = 0; b < nb; ++b) {
        int curb = b & 1;
        bool have_next = (b + 1) < nb;
        if (have_next) {                       // issue next-slice loads (no wait yet)
            int nsbase  = (b + 1) << BSHIFT;
            int nscount = min(BSIZE, n_part - nsbase);
            #pragma unroll
            for (int i = 0; i < 4; ++i) {
                int fi = (threadIdx.x + 1024 * i) * 4;
                if (fi + 3 < nscount) st[i] = *(const floatx4*)(gamma_in + nsbase + fi);
                else {
                    floatx4 z = {0.f, 0.f, 0.f, 0.f};
                    for (int e = 0; e < 4; ++e) if (fi + e < nscount) z[e] = gamma_in[nsbase + fi + e];
                    st[i] = z;
                }
            }
        }
        // gather phase on buf curb
        int bn = b * n_part;
        int p0A = 0, p1A = 0, p0B = 0, p1B = 0, p0C = 0, p1C = 0, p0D = 0, p1D = 0;
        if (vA) { p0A = OFF[bn + rA]; p1A = OFF[bn + rA + 1]; }
        if (vB) { p0B = OFF[bn + rB]; p1B = OFF[bn + rB + 1]; }
        if (vC) { p0C = OFF[bn + rC]; p1C = OFF[bn + rC + 1]; }
        if (vD) { p0D = OFF[bn + rD]; p1D = OFF[bn + rD + 1]; }
        for (int j = p0A + sub; j < p1A; j += 4) {
            unsigned p = pack[j]; aA += (float)(p >> 14) * s[curb][p & LMASK];
        }
        for (int j = p0B + sub; j < p1B; j += 4) {
            unsigned p = pack[j]; aB += (float)(p >> 14) * s[curb][p & LMASK];
        }
        for (int j = p0C + sub; j < p1C; j += 4) {
            unsigned p = pack[j]; aC += (float)(p >> 14) * s[curb][p & LMASK];
        }
        for (int j = p0D + sub; j < p1D; j += 4) {
            unsigned p = pack[j]; aD += (float)(p >> 14) * s[curb][p & LMASK];
        }
        __syncthreads();                       // all reads of buf curb^1's old content done
        if (have_next) {
            #pragma unroll
            for (int i = 0; i < 4; ++i)
                *(floatx4*)(&s[curb ^ 1][(threadIdx.x + 1024 * i) * 4]) = st[i];
            __syncthreads();
        }
    }
    aA += __shfl_down(aA, 2); aA += __shfl_down(aA, 1);
    aB += __shfl_down(aB, 2); aB += __shfl_down(aB, 1);
    aC += __shfl_down(aC, 2); aC += __shfl_down(aC, 1);
    aD += __shfl_down(aD, 2); aD += __shfl_down(aD, 1);
    if (sub == 0) {
        if (vA) gamma_out[rA] = clip01(aA * Q_INV + residual[rA]);
        if (vB) gamma_out[rB] = clip01(aB * Q_INV + residual[rB]);
        if (vC) gamma_out[rC] = clip01(aC * Q_INV + residual[rC]);
        if (vD) gamma_out[rD] = clip01(aD * Q_INV + residual[rD]);
    }
}

// ---------- fallback kernels (R4-proven path) ----------
#define NBR_MASK 0x3FFFFu
__global__ void pack_kernel(const float* __restrict__ bl, const int* __restrict__ nbr,
                            unsigned* __restrict__ pack, int n_edges) {
    int i = (blockIdx.x * blockDim.x + threadIdx.x) * 4;
    if (i + 3 < n_edges) {
        float4 b = *(const float4*)(bl + i);
        int4   v = *(const int4*)(nbr + i);
        uint4  o;
        o.x = (quantize(b.x) << 18) | (unsigned)v.x;
        o.y = (quantize(b.y) << 18) | (unsigned)v.y;
        o.z = (quantize(b.z) << 18) | (unsigned)v.z;
        o.w = (quantize(b.w) << 18) | (unsigned)v.w;
        *(uint4*)(pack + i) = o;
    } else {
        for (; i < n_edges; ++i) pack[i] = (quantize(bl[i]) << 18) | (unsigned)nbr[i];
    }
}

__global__ void rowsum_g1(const unsigned* __restrict__ pack,
                          const int* __restrict__ row_ptr,
                          float* __restrict__ residual, float* __restrict__ g1,
                          int n_part) {
    int idx  = blockIdx.x * blockDim.x + threadIdx.x;
    int row  = idx >> 6;
    int lane = threadIdx.x & 63;
    if (row >= n_part) return;
    int start = row_ptr[row], end = row_ptr[row + 1];
    float acc = 0.0f;
    for (int e = start + lane; e < end; e += 64) acc += (float)(pack[e] >> 18);
    #pragma unroll
    for (int off = 32; off > 0; off >>= 1) acc += __shfl_down(acc, off);
    if (lane == 0) {
        float r = 1.0f - acc * Q_INV;
        residual[row] = r;
        g1[row] = clip01(r);
    }
}

__global__ __launch_bounds__(256) void step4(const float* __restrict__ gamma_in,
                                             const unsigned* __restrict__ pack,
                                             const int* __restrict__ row_ptr,
                                             const float* __restrict__ residual,
                                             float* __restrict__ gamma_out, int n_part) {
    int tid = blockIdx.x * 256 + threadIdx.x;
    int row = tid >> 2;
    int sub = tid & 3;
    if (row >= n_part) return;
    int start = row_ptr[row], end = row_ptr[row + 1];
    float acc = 0.0f;
    int abase = (start + 3) & ~3;
    {
        int j = start + sub;
        if (j < abase && j < end) {
            unsigned p = pack[j];
            acc += (float)(p >> 18) * gamma_in[p & NBR_MASK];
        }
    }
    int i = abase + sub * 4;
    #pragma unroll 2
    for (; i + 3 < end; i += 16) {
        uint4 p = *(const uint4*)(pack + i);
        float g0 = gamma_in[p.x & NBR_MASK];
        float g1v = gamma_in[p.y & NBR_MASK];
        float g2 = gamma_in[p.z & NBR_MASK];
        float g3 = gamma_in[p.w & NBR_MASK];
        acc += (float)(p.x >> 18) * g0 + (float)(p.y >> 18) * g1v
             + (float)(p.z >> 18) * g2 + (float)(p.w >> 18) * g3;
    }
    for (int j = i; j < end && j < i + 4; ++j) {
        unsigned p = pack[j];
        acc += (float)(p >> 18) * gamma_in[p & NBR_MASK];
    }
    acc += __shfl_down(acc, 2);
    acc += __shfl_down(acc, 1);
    if (sub == 0) {
        float g = acc * Q_INV + residual[row];
        gamma_out[row] = clip01(g);
    }
}

__global__ __launch_bounds__(256) void step4_raw(const float* __restrict__ gamma_in,
                                                 const float* __restrict__ bl,
                                                 const int* __restrict__ nbr,
                                                 const int* __restrict__ row_ptr,
                                                 const float* __restrict__ residual,
                                                 float* __restrict__ gamma_out, int n_part) {
    int tid = blockIdx.x * 256 + threadIdx.x;
    int row = tid >> 2;
    int sub = tid & 3;
    if (row >= n_part) return;
    int start = row_ptr[row], end = row_ptr[row + 1];
    float acc = 0.0f;
    for (int j = start + sub; j < end; j += 4)
        acc += bl[j] * gamma_in[nbr[j]];
    acc += __shfl_down(acc, 2);
    acc += __shfl_down(acc, 1);
    if (sub == 0) {
        float g = acc + residual[row];
        gamma_out[row] = clip01(g);
    }
}

__global__ void residual_raw(const float* __restrict__ bl,
                             const int* __restrict__ row_ptr,
                             float* __restrict__ residual, float* __restrict__ g1,
                             int n_part) {
    int idx  = blockIdx.x * blockDim.x + threadIdx.x;
    int row  = idx >> 6;
    int lane = threadIdx.x & 63;
    if (row >= n_part) return;
    int start = row_ptr[row], end = row_ptr[row + 1];
    float acc = 0.0f;
    for (int e = start + lane; e < end; e += 64) acc += bl[e];
    #pragma unroll
    for (int off = 32; off > 0; off >>= 1) acc += __shfl_down(acc, off);
    if (lane == 0) {
        float r = 1.0f - acc;
        residual[row] = r;
        g1[row] = clip01(r);
    }
}

extern "C" void kernel_launch(void* const* d_in, const int* in_sizes, int n_in,
                              void* d_out, int out_size, void* d_ws, size_t ws_size,
                              hipStream_t stream) {
    const float* bl  = (const float*)d_in[1];
    const int*   nbr = (const int*)d_in[2];
    const int*   seg = (const int*)d_in[3];
    const int n_part  = in_sizes[0];
    const int n_edges = in_sizes[1];
    const int horizon = 10;
    float* gout = (float*)d_out;
    const int BLK = 256;

    auto align256 = [](size_t x) { return (x + 255) & ~(size_t)255; };
    char* ws = (char*)d_ws;
    size_t off = 0;
    int* row_ptr = (int*)(ws + off);      off += align256((size_t)(n_part + 1) * 4);
    float* residual = (float*)(ws + off); off += align256((size_t)n_part * 4);
    float* bufX = (float*)(ws + off);     off += align256((size_t)n_part * 4);
    float* bufY = (float*)(ws + off);     off += align256((size_t)n_part * 4);
    size_t off_base = off;

    int nb = (n_part + BSIZE - 1) >> BSHIFT;
    int cells = nb * n_part;
    int SB = (cells + 8191) / 8192;
    int rpb = (n_part + 255) / 256;        // rows per block for step_db (<= 1024)

    // bucket-major layout: OFF (cells+1), part (<=1024), pack (n_edges)
    size_t off_off  = off_base;
    size_t part_off = off_off + align256(((size_t)cells + 1) * 4);
    size_t packb_off = part_off + align256(1024 * 4);
    size_t need_bm = packb_off + align256((size_t)(n_edges + 4) * 4);
    // fallback packed layout
    size_t packp_off = off_base;
    size_t need_packed = packp_off + align256((size_t)(n_edges + 4) * 4);

    bool use_bm = (nb >= 1) && (nb <= 15) && (SB <= 1024) && (rpb <= 1024)
                  && (ws_size >= need_bm);
    bool use_packed = ws_size >= need_packed;

    build_rowptr<<<dim3((n_edges + BLK - 1) / BLK), dim3(BLK), 0, stream>>>(
        seg, row_ptr, n_edges, n_part);

    int wave_row_blocks = (n_part * 64 + BLK - 1) / BLK;
    int step_blocks     = (n_part * 4  + BLK - 1) / BLK;

    if (use_bm) {
        int* OFF = (int*)(ws + off_off);
        int* part = (int*)(ws + part_off);
        unsigned* pack = (unsigned*)(ws + packb_off);
        count_buckets<<<dim3(wave_row_blocks), dim3(BLK), 0, stream>>>(
            nbr, row_ptr, OFF, n_part, nb);
        scan_part<<<dim3(SB), dim3(1024), 0, stream>>>(OFF, part, cells);
        scan_top<<<dim3(1), dim3(1024), 0, stream>>>(part, OFF, SB, cells, n_edges);
        scan_apply<<<dim3(SB), dim3(1024), 0, stream>>>(OFF, part, cells);
        scatter_pack<<<dim3(wave_row_blocks), dim3(BLK), 0, stream>>>(
            bl, nbr, row_ptr, OFF, pack, residual, bufX, n_part, nb);
        int grid = (n_part + rpb - 1) / rpb;   // ~256 blocks, 1/CU
        const float* cur = bufX;               // gamma1 = clip(residual), gamma0 == 0
        for (int t = 2; t <= horizon; ++t) {
            float* dst = (t == horizon) ? gout : ((t & 1) ? bufX : bufY);
            step_db<<<dim3(grid), dim3(1024), 0, stream>>>(
                cur, pack, OFF, residual, dst, n_part, nb, rpb);
            cur = dst;
        }
        if (cur != gout)
            (void)hipMemcpyAsync(gout, cur, (size_t)n_part * 4, hipMemcpyDeviceToDevice, stream);
    } else if (use_packed) {
        unsigned* pack = (unsigned*)(ws + packp_off);
        int pack_threads = (n_edges + 3) / 4;
        pack_kernel<<<dim3((pack_threads + BLK - 1) / BLK), dim3(BLK), 0, stream>>>(
            bl, nbr, pack, n_edges);
        rowsum_g1<<<dim3(wave_row_blocks), dim3(BLK), 0, stream>>>(
            pack, row_ptr, residual, bufX, n_part);
        const float* cur = bufX;
        for (int t = 2; t <= horizon; ++t) {
            float* dst = (t == horizon) ? gout : ((t & 1) ? bufX : bufY);
            step4<<<dim3(step_blocks), dim3(BLK), 0, stream>>>(
                cur, pack, row_ptr, residual, dst, n_part);
            cur = dst;
        }
        if (cur != gout)
            (void)hipMemcpyAsync(gout, cur, (size_t)n_part * 4, hipMemcpyDeviceToDevice, stream);
    } else {
        residual_raw<<<dim3(wave_row_blocks), dim3(BLK), 0, stream>>>(
            bl, row_ptr, residual, bufX, n_part);
        const float* cur = bufX;
        for (int t = 2; t <= horizon; ++t) {
            float* dst = (t == horizon) ? gout : ((t & 1) ? bufX : bufY);
            step4_raw<<<dim3(step_blocks), dim3(BLK), 0, stream>>>(
                cur, bl, nbr, row_ptr, residual, dst, n_part);
            cur = dst;
        }
        if (cur != gout)
            (void)hipMemcpyAsync(gout, cur, (size_t)n_part * 4, hipMemcpyDeviceToDevice, stream);
    }
}

// Round 7
// 1043.409 us; speedup vs baseline: 1.5235x; 1.0482x over previous
//
#include <hip/hip_runtime.h>

// gamma_{t+1}[j] = clip(sum_e w[e]*gamma_t[nbr[e]] + residual[j], 0, 1), 10 steps.
// R11: consecutive-rows groups + contiguous-range gather (step_cg).
// R10 post-mortem: step_db's 4 sequential per-row segment loops (~2.5 iters each,
// rows 256 apart) left short serial dependent load chains -> ~95us/step.
// Fix: each 4-lane group owns 3-4 CONSECUTIVE rows; in bucket-major layout their
// bucket-b segments form ONE contiguous range. One loop per phase per group,
// branchless row attribution vs 3 interior OFF boundaries, 4 accs shfl-reduced.
// LDS slice double-buffer identical to R10 (proven).
// Edge pack u32: bits[27:14] = round(bl*2^21) (bl < 2^-7), bits[13:0] = nbr&0x3FFF.

#define BSHIFT 14
#define BSIZE  16384                   // floats per slice (64 KB)
#define LMASK  0x3FFFu
#define Q_SCALE 2097152.0f            // 2^21
#define Q_INV   4.76837158203125e-07f // 2^-21

typedef float floatx4 __attribute__((ext_vector_type(4)));
typedef int   intx4   __attribute__((ext_vector_type(4)));

__device__ __forceinline__ unsigned quantize(float b) {
    unsigned q = (unsigned)(b * Q_SCALE + 0.5f);
    return q > 16383u ? 16383u : q;
}
__device__ __forceinline__ float clip01(float x) { return fminf(fmaxf(x, 0.f), 1.f); }

// class mask: lanes whose 4-bit bucket id equals mine (4 ballots).
__device__ __forceinline__ unsigned long long class_mask(int b) {
    unsigned long long m = ~0ULL;
    #pragma unroll
    for (int k = 0; k < 4; ++k) {
        unsigned long long bb = __ballot((b >> k) & 1);
        m &= ((b >> k) & 1) ? bb : ~bb;
    }
    return m;
}

// row_ptr[j] = first edge index with seg >= j.
__global__ void build_rowptr(const int* __restrict__ seg, int* __restrict__ row_ptr,
                             int n_edges, int n_part) {
    int e = blockIdx.x * blockDim.x + threadIdx.x;
    if (e >= n_edges) return;
    int s = seg[e];
    int sprev = (e == 0) ? -1 : seg[e - 1];
    for (int j = sprev + 1; j <= s; ++j) row_ptr[j] = e;
    if (e == n_edges - 1)
        for (int j = s + 1; j <= n_part; ++j) row_ptr[j] = n_edges;
}

// P1: one wave per row -> per-bucket counts into OFF[b*n_part + row].
__global__ __launch_bounds__(256) void count_buckets(const int* __restrict__ nbr,
        const int* __restrict__ row_ptr, int* __restrict__ OFF,
        int n_part, int nb) {
    __shared__ int cnt[4][16];
    int wid  = threadIdx.x >> 6;
    int lane = threadIdx.x & 63;
    int row  = (blockIdx.x * 256 + threadIdx.x) >> 6;
    bool rv  = row < n_part;
    if (lane < 16) cnt[wid][lane] = 0;
    __syncthreads();
    if (rv) {
        int start = row_ptr[row], deg = row_ptr[row + 1] - start;
        for (int base = 0; base < deg; base += 64) {
            int j = base + lane;
            int b = (j < deg) ? (nbr[start + j] >> BSHIFT) : 15;
            unsigned long long m = class_mask(b);
            int rank = __popcll(m & ((1ULL << lane) - 1ULL));
            if (rank == 0 && b != 15) atomicAdd(&cnt[wid][b], __popcll(m));
        }
    }
    __syncthreads();
    if (rv && lane < nb) OFF[(size_t)lane * n_part + row] = cnt[wid][lane];
}

// P2a: per-chunk (8192 cells) sums.
__global__ __launch_bounds__(1024) void scan_part(const int* __restrict__ OFF,
        int* __restrict__ part, int cells) {
    __shared__ int wl[16];
    int base = blockIdx.x * 8192 + threadIdx.x * 8;
    int s = 0;
    if (base + 8 <= cells) {
        intx4 a = *(const intx4*)(OFF + base);
        intx4 b = *(const intx4*)(OFF + base + 4);
        s = a.x + a.y + a.z + a.w + b.x + b.y + b.z + b.w;
    } else {
        for (int k = 0; k < 8; ++k) if (base + k < cells) s += OFF[base + k];
    }
    int incl = s;
    #pragma unroll
    for (int d = 1; d < 64; d <<= 1) { int t = __shfl_up(incl, d); if ((threadIdx.x & 63) >= d) incl += t; }
    if ((threadIdx.x & 63) == 63) wl[threadIdx.x >> 6] = incl;
    __syncthreads();
    if (threadIdx.x == 0) {
        int tot = 0;
        for (int w = 0; w < 16; ++w) tot += wl[w];
        part[blockIdx.x] = tot;
    }
}

// P2b: exclusive scan of part[0..SB) in one block; also OFF[cells] = n_edges.
__global__ __launch_bounds__(1024) void scan_top(int* __restrict__ part,
        int* __restrict__ OFF, int SB, int cells, int n_edges) {
    __shared__ int a[1024];
    int v = (threadIdx.x < SB) ? part[threadIdx.x] : 0;
    a[threadIdx.x] = v;
    __syncthreads();
    for (int off = 1; off < 1024; off <<= 1) {
        int t = (threadIdx.x >= off) ? a[threadIdx.x - off] : 0;
        __syncthreads();
        a[threadIdx.x] += t;
        __syncthreads();
    }
    if (threadIdx.x < SB) part[threadIdx.x] = a[threadIdx.x] - v;
    if (threadIdx.x == 0) OFF[cells] = n_edges;
}

// P2c: in-place exclusive scan of each chunk, offset by part[blk].
__global__ __launch_bounds__(1024) void scan_apply(int* __restrict__ OFF,
        const int* __restrict__ part, int cells) {
    __shared__ int wl[16];
    int base = blockIdx.x * 8192 + threadIdx.x * 8;
    int v[8]; int s = 0;
    #pragma unroll
    for (int k = 0; k < 8; ++k) {
        v[k] = (base + k < cells) ? OFF[base + k] : 0;
        s += v[k];
    }
    int lane = threadIdx.x & 63, wid = threadIdx.x >> 6;
    int incl = s;
    #pragma unroll
    for (int d = 1; d < 64; d <<= 1) { int t = __shfl_up(incl, d); if (lane >= d) incl += t; }
    if (lane == 63) wl[wid] = incl;
    __syncthreads();
    if (threadIdx.x == 0) {
        int run = 0;
        for (int w = 0; w < 16; ++w) { int t = wl[w]; wl[w] = run; run += t; }
    }
    __syncthreads();
    int run = part[blockIdx.x] + wl[wid] + (incl - s);
    #pragma unroll
    for (int k = 0; k < 8; ++k) {
        if (base + k < cells) OFF[base + k] = run;
        run += v[k];
    }
}

// P3: one wave per row: class-mask rank scatter into bucket-major pack + residual/g1.
__global__ __launch_bounds__(256) void scatter_pack(const float* __restrict__ bl,
        const int* __restrict__ nbr, const int* __restrict__ row_ptr,
        const int* __restrict__ OFF, unsigned* __restrict__ pack,
        float* __restrict__ residual, float* __restrict__ g1,
        int n_part, int nb) {
    __shared__ int cur[4][16];
    int wid  = threadIdx.x >> 6;
    int lane = threadIdx.x & 63;
    int row  = (blockIdx.x * 256 + threadIdx.x) >> 6;
    bool rv  = row < n_part;
    if (lane < 16) cur[wid][lane] = (rv && lane < nb) ? OFF[(size_t)lane * n_part + row] : 0;
    __syncthreads();
    if (rv) {
        int start = row_ptr[row], deg = row_ptr[row + 1] - start;
        float accq = 0.f;
        for (int base = 0; base < deg; base += 64) {
            int j = base + lane;
            int nb_i = 0; float bv = 0.f; int b = 15;
            if (j < deg) { nb_i = nbr[start + j]; bv = bl[start + j]; b = nb_i >> BSHIFT; }
            unsigned long long m = class_mask(b);
            int rank = __popcll(m & ((1ULL << lane) - 1ULL));
            int leader_lane = (int)__ffsll((long long)m) - 1;
            int old = 0;
            if (rank == 0 && b != 15) old = atomicAdd(&cur[wid][b], __popcll(m));
            int basep = __shfl(old, leader_lane);
            if (b != 15) {
                unsigned q = quantize(bv);
                accq += (float)q;
                pack[basep + rank] = (q << 14) | ((unsigned)nb_i & LMASK);
            }
        }
        #pragma unroll
        for (int off = 32; off > 0; off >>= 1) accq += __shfl_down(accq, off);
        if (lane == 0) {
            float r = 1.0f - accq * Q_INV;
            residual[row] = r;
            g1[row] = clip01(r);
        }
    }
}

// Step: each 4-lane group owns 3-4 consecutive rows; per bucket phase it walks
// ONE contiguous pack range with branchless row attribution. Slices double-buffered.
__global__ __launch_bounds__(1024) void step_cg(const float* __restrict__ gamma_in,
        const unsigned* __restrict__ pack, const int* __restrict__ OFF,
        const float* __restrict__ residual, float* __restrict__ gamma_out,
        int n_part, int nb, int rpb) {
    __shared__ float s[2][BSIZE];
    int g   = threadIdx.x >> 2;            // 0..255
    int sub = threadIdx.x & 3;
    int r0  = blockIdx.x * rpb;
    int rlo = r0 + ((g * rpb) >> 8);       // balanced split of rpb rows over 256 groups
    int rhi = r0 + (((g + 1) * rpb) >> 8);
    if (rhi > n_part) rhi = n_part;
    bool gv = rlo < rhi;                   // group has rows
    float acc0 = 0.f, acc1 = 0.f, acc2 = 0.f, acc3 = 0.f;

    floatx4 st[4];
    // prologue: stage slice 0 and write to buf 0
    {
        int scount = min(BSIZE, n_part);
        #pragma unroll
        for (int i = 0; i < 4; ++i) {
            int fi = (threadIdx.x + 1024 * i) * 4;
            if (fi + 3 < scount) st[i] = *(const floatx4*)(gamma_in + fi);
            else {
                floatx4 z = {0.f, 0.f, 0.f, 0.f};
                for (int e = 0; e < 4; ++e) if (fi + e < scount) z[e] = gamma_in[fi + e];
                st[i] = z;
            }
        }
        #pragma unroll
        for (int i = 0; i < 4; ++i)
            *(floatx4*)(&s[0][(threadIdx.x + 1024 * i) * 4]) = st[i];
    }
    __syncthreads();

    for (int b = 0; b < nb; ++b) {
        int curb = b & 1;
        bool have_next = (b + 1) < nb;
        if (have_next) {                   // issue next-slice loads (no wait yet)
            int nsbase  = (b + 1) << BSHIFT;
            int nscount = min(BSIZE, n_part - nsbase);
            #pragma unroll
            for (int i = 0; i < 4; ++i) {
                int fi = (threadIdx.x + 1024 * i) * 4;
                if (fi + 3 < nscount) st[i] = *(const floatx4*)(gamma_in + nsbase + fi);
                else {
                    floatx4 z = {0.f, 0.f, 0.f, 0.f};
                    for (int e = 0; e < 4; ++e) if (fi + e < nscount) z[e] = gamma_in[nsbase + fi + e];
                    st[i] = z;
                }
            }
        }
        if (gv) {
            int bn = b * n_part;
            int gs = OFF[bn + rlo];
            int ge = OFF[bn + rhi];
            int b1 = (rlo + 1 < rhi) ? OFF[bn + rlo + 1] : ge;
            int b2 = (rlo + 2 < rhi) ? OFF[bn + rlo + 2] : ge;
            int b3 = (rlo + 3 < rhi) ? OFF[bn + rlo + 3] : ge;
            const float* sc = s[curb];
            for (int e0 = gs + 4 * sub; e0 < ge; e0 += 16) {
                #pragma unroll
                for (int k = 0; k < 4; ++k) {
                    int e = e0 + k;
                    if (e < ge) {
                        unsigned p = pack[e];
                        float v = (float)(p >> 14) * sc[p & LMASK];
                        acc0 += (e <  b1) ? v : 0.f;
                        acc1 += (e >= b1 && e < b2) ? v : 0.f;
                        acc2 += (e >= b2 && e < b3) ? v : 0.f;
                        acc3 += (e >= b3) ? v : 0.f;
                    }
                }
            }
        }
        __syncthreads();                   // all gathers on s[curb] done
        if (have_next) {
            #pragma unroll
            for (int i = 0; i < 4; ++i)
                *(floatx4*)(&s[curb ^ 1][(threadIdx.x + 1024 * i) * 4]) = st[i];
            __syncthreads();
        }
    }
    // reduce each accumulator over the 4-lane group (lane 0 holds the sum)
    acc0 += __shfl_down(acc0, 2); acc0 += __shfl_down(acc0, 1);
    acc1 += __shfl_down(acc1, 2); acc1 += __shfl_down(acc1, 1);
    acc2 += __shfl_down(acc2, 2); acc2 += __shfl_down(acc2, 1);
    acc3 += __shfl_down(acc3, 2); acc3 += __shfl_down(acc3, 1);
    if (sub == 0 && gv) {
        if (rlo     < rhi) gamma_out[rlo]     = clip01(acc0 * Q_INV + residual[rlo]);
        if (rlo + 1 < rhi) gamma_out[rlo + 1] = clip01(acc1 * Q_INV + residual[rlo + 1]);
        if (rlo + 2 < rhi) gamma_out[rlo + 2] = clip01(acc2 * Q_INV + residual[rlo + 2]);
        if (rlo + 3 < rhi) gamma_out[rlo + 3] = clip01(acc3 * Q_INV + residual[rlo + 3]);
    }
}

// ---------- fallback kernels (R4-proven path) ----------
#define NBR_MASK 0x3FFFFu
__global__ void pack_kernel(const float* __restrict__ bl, const int* __restrict__ nbr,
                            unsigned* __restrict__ pack, int n_edges) {
    int i = (blockIdx.x * blockDim.x + threadIdx.x) * 4;
    if (i + 3 < n_edges) {
        float4 b = *(const float4*)(bl + i);
        int4   v = *(const int4*)(nbr + i);
        uint4  o;
        o.x = (quantize(b.x) << 18) | (unsigned)v.x;
        o.y = (quantize(b.y) << 18) | (unsigned)v.y;
        o.z = (quantize(b.z) << 18) | (unsigned)v.z;
        o.w = (quantize(b.w) << 18) | (unsigned)v.w;
        *(uint4*)(pack + i) = o;
    } else {
        for (; i < n_edges; ++i) pack[i] = (quantize(bl[i]) << 18) | (unsigned)nbr[i];
    }
}

__global__ void rowsum_g1(const unsigned* __restrict__ pack,
                          const int* __restrict__ row_ptr,
                          float* __restrict__ residual, float* __restrict__ g1,
                          int n_part) {
    int idx  = blockIdx.x * blockDim.x + threadIdx.x;
    int row  = idx >> 6;
    int lane = threadIdx.x & 63;
    if (row >= n_part) return;
    int start = row_ptr[row], end = row_ptr[row + 1];
    float acc = 0.0f;
    for (int e = start + lane; e < end; e += 64) acc += (float)(pack[e] >> 18);
    #pragma unroll
    for (int off = 32; off > 0; off >>= 1) acc += __shfl_down(acc, off);
    if (lane == 0) {
        float r = 1.0f - acc * Q_INV;
        residual[row] = r;
        g1[row] = clip01(r);
    }
}

__global__ __launch_bounds__(256) void step4(const float* __restrict__ gamma_in,
                                             const unsigned* __restrict__ pack,
                                             const int* __restrict__ row_ptr,
                                             const float* __restrict__ residual,
                                             float* __restrict__ gamma_out, int n_part) {
    int tid = blockIdx.x * 256 + threadIdx.x;
    int row = tid >> 2;
    int sub = tid & 3;
    if (row >= n_part) return;
    int start = row_ptr[row], end = row_ptr[row + 1];
    float acc = 0.0f;
    int abase = (start + 3) & ~3;
    {
        int j = start + sub;
        if (j < abase && j < end) {
            unsigned p = pack[j];
            acc += (float)(p >> 18) * gamma_in[p & NBR_MASK];
        }
    }
    int i = abase + sub * 4;
    #pragma unroll 2
    for (; i + 3 < end; i += 16) {
        uint4 p = *(const uint4*)(pack + i);
        float g0 = gamma_in[p.x & NBR_MASK];
        float g1v = gamma_in[p.y & NBR_MASK];
        float g2 = gamma_in[p.z & NBR_MASK];
        float g3 = gamma_in[p.w & NBR_MASK];
        acc += (float)(p.x >> 18) * g0 + (float)(p.y >> 18) * g1v
             + (float)(p.z >> 18) * g2 + (float)(p.w >> 18) * g3;
    }
    for (int j = i; j < end && j < i + 4; ++j) {
        unsigned p = pack[j];
        acc += (float)(p >> 18) * gamma_in[p & NBR_MASK];
    }
    acc += __shfl_down(acc, 2);
    acc += __shfl_down(acc, 1);
    if (sub == 0) {
        float g = acc * Q_INV + residual[row];
        gamma_out[row] = clip01(g);
    }
}

__global__ __launch_bounds__(256) void step4_raw(const float* __restrict__ gamma_in,
                                                 const float* __restrict__ bl,
                                                 const int* __restrict__ nbr,
                                                 const int* __restrict__ row_ptr,
                                                 const float* __restrict__ residual,
                                                 float* __restrict__ gamma_out, int n_part) {
    int tid = blockIdx.x * 256 + threadIdx.x;
    int row = tid >> 2;
    int sub = tid & 3;
    if (row >= n_part) return;
    int start = row_ptr[row], end = row_ptr[row + 1];
    float acc = 0.0f;
    for (int j = start + sub; j < end; j += 4)
        acc += bl[j] * gamma_in[nbr[j]];
    acc += __shfl_down(acc, 2);
    acc += __shfl_down(acc, 1);
    if (sub == 0) {
        float g = acc + residual[row];
        gamma_out[row] = clip01(g);
    }
}

__global__ void residual_raw(const float* __restrict__ bl,
                             const int* __restrict__ row_ptr,
                             float* __restrict__ residual, float* __restrict__ g1,
                             int n_part) {
    int idx  = blockIdx.x * blockDim.x + threadIdx.x;
    int row  = idx >> 6;
    int lane = threadIdx.x & 63;
    if (row >= n_part) return;
    int start = row_ptr[row], end = row_ptr[row + 1];
    float acc = 0.0f;
    for (int e = start + lane; e < end; e += 64) acc += bl[e];
    #pragma unroll
    for (int off = 32; off > 0; off >>= 1) acc += __shfl_down(acc, off);
    if (lane == 0) {
        float r = 1.0f - acc;
        residual[row] = r;
        g1[row] = clip01(r);
    }
}

extern "C" void kernel_launch(void* const* d_in, const int* in_sizes, int n_in,
                              void* d_out, int out_size, void* d_ws, size_t ws_size,
                              hipStream_t stream) {
    const float* bl  = (const float*)d_in[1];
    const int*   nbr = (const int*)d_in[2];
    const int*   seg = (const int*)d_in[3];
    const int n_part  = in_sizes[0];
    const int n_edges = in_sizes[1];
    const int horizon = 10;
    float* gout = (float*)d_out;
    const int BLK = 256;

    auto align256 = [](size_t x) { return (x + 255) & ~(size_t)255; };
    char* ws = (char*)d_ws;
    size_t off = 0;
    int* row_ptr = (int*)(ws + off);      off += align256((size_t)(n_part + 1) * 4);
    float* residual = (float*)(ws + off); off += align256((size_t)n_part * 4);
    float* bufX = (float*)(ws + off);     off += align256((size_t)n_part * 4);
    float* bufY = (float*)(ws + off);     off += align256((size_t)n_part * 4);
    size_t off_base = off;

    int nb = (n_part + BSIZE - 1) >> BSHIFT;
    int cells = nb * n_part;
    int SB = (cells + 8191) / 8192;
    int rpb = (n_part + 255) / 256;        // rows per block for step_cg (<= 1024)

    // bucket-major layout: OFF (cells+1), part (<=1024), pack (n_edges)
    size_t off_off  = off_base;
    size_t part_off = off_off + align256(((size_t)cells + 1) * 4);
    size_t packb_off = part_off + align256(1024 * 4);
    size_t need_bm = packb_off + align256((size_t)(n_edges + 4) * 4);
    // fallback packed layout
    size_t packp_off = off_base;
    size_t need_packed = packp_off + align256((size_t)(n_edges + 4) * 4);

    bool use_bm = (nb >= 1) && (nb <= 15) && (SB <= 1024) && (rpb <= 1024)
                  && (ws_size >= need_bm);
    bool use_packed = ws_size >= need_packed;

    build_rowptr<<<dim3((n_edges + BLK - 1) / BLK), dim3(BLK), 0, stream>>>(
        seg, row_ptr, n_edges, n_part);

    int wave_row_blocks = (n_part * 64 + BLK - 1) / BLK;
    int step_blocks     = (n_part * 4  + BLK - 1) / BLK;

    if (use_bm) {
        int* OFF = (int*)(ws + off_off);
        int* part = (int*)(ws + part_off);
        unsigned* pack = (unsigned*)(ws + packb_off);
        count_buckets<<<dim3(wave_row_blocks), dim3(BLK), 0, stream>>>(
            nbr, row_ptr, OFF, n_part, nb);
        scan_part<<<dim3(SB), dim3(1024), 0, stream>>>(OFF, part, cells);
        scan_top<<<dim3(1), dim3(1024), 0, stream>>>(part, OFF, SB, cells, n_edges);
        scan_apply<<<dim3(SB), dim3(1024), 0, stream>>>(OFF, part, cells);
        scatter_pack<<<dim3(wave_row_blocks), dim3(BLK), 0, stream>>>(
            bl, nbr, row_ptr, OFF, pack, residual, bufX, n_part, nb);
        int grid = (n_part + rpb - 1) / rpb;   // == 256 for this shape
        const float* cur = bufX;               // gamma1 = clip(residual), gamma0 == 0
        for (int t = 2; t <= horizon; ++t) {
            float* dst = (t == horizon) ? gout : ((t & 1) ? bufX : bufY);
            step_cg<<<dim3(grid), dim3(1024), 0, stream>>>(
                cur, pack, OFF, residual, dst, n_part, nb, rpb);
            cur = dst;
        }
        if (cur != gout)
            (void)hipMemcpyAsync(gout, cur, (size_t)n_part * 4, hipMemcpyDeviceToDevice, stream);
    } else if (use_packed) {
        unsigned* pack = (unsigned*)(ws + packp_off);
        int pack_threads = (n_edges + 3) / 4;
        pack_kernel<<<dim3((pack_threads + BLK - 1) / BLK), dim3(BLK), 0, stream>>>(
            bl, nbr, pack, n_edges);
        rowsum_g1<<<dim3(wave_row_blocks), dim3(BLK), 0, stream>>>(
            pack, row_ptr, residual, bufX, n_part);
        const float* cur = bufX;
        for (int t = 2; t <= horizon; ++t) {
            float* dst = (t == horizon) ? gout : ((t & 1) ? bufX : bufY);
            step4<<<dim3(step_blocks), dim3(BLK), 0, stream>>>(
                cur, pack, row_ptr, residual, dst, n_part);
            cur = dst;
        }
        if (cur != gout)
            (void)hipMemcpyAsync(gout, cur, (size_t)n_part * 4, hipMemcpyDeviceToDevice, stream);
    } else {
        residual_raw<<<dim3(wave_row_blocks), dim3(BLK), 0, stream>>>(
            bl, row_ptr, residual, bufX, n_part);
        const float* cur = bufX;
        for (int t = 2; t <= horizon; ++t) {
            float* dst = (t == horizon) ? gout : ((t & 1) ? bufX : bufY);
            step4_raw<<<dim3(step_blocks), dim3(BLK), 0, stream>>>(
                cur, bl, nbr, row_ptr, residual, dst, n_part);
            cur = dst;
        }
        if (cur != gout)
            (void)hipMemcpyAsync(gout, cur, (size_t)n_part * 4, hipMemcpyDeviceToDevice, stream);
    }
}